// Round 13
// baseline (160.543 us; speedup 1.0000x reference)
//
#include <hip/hip_runtime.h>
#include <stdint.h>

#define RES_DIM 8192
#define BATCH   128
#define NNZ     1342177
#define LEAK    0.6f
#define BIAS    1.6f

#define CONV_BLOCKS 1024                          // (RES_DIM/32) * (BATCH/32)
#define BND_THREADS ((NNZ + 3) / 4)               // 335545
#define BND_BLOCKS  ((BND_THREADS + 255) / 256)   // 1311

// ---------------------------------------------------------------------------
// helpers
// ---------------------------------------------------------------------------
__device__ __forceinline__ float fast_tanh(float x) {
    float e = __expf(2.0f * x);
    return 1.0f - 2.0f / (e + 1.0f);
}

__device__ __forceinline__ uint32_t f32_to_bf16_rne(float f) {
    uint32_t u = __float_as_uint(f);
    return (u + 0x7fffu + ((u >> 16) & 1u)) >> 16;
}

// ---------------------------------------------------------------------------
// Kernel 1 (fused prep): conv (bf16-pack transpose) + rowptr boundary detect
// ---------------------------------------------------------------------------
__global__ __launch_bounds__(256) void prep_kernel(
    const float* __restrict__ in, uint32_t* __restrict__ st2,
    const int* __restrict__ rows, int* __restrict__ row_start) {
    if (blockIdx.x < CONV_BLOCKS) {
        __shared__ float tile[32][33];
        const int bx = blockIdx.x & 255;     // r-tile
        const int by = blockIdx.x >> 8;      // b-tile
        const int tx = threadIdx.x & 31, ty = threadIdx.x >> 5;  // 32x8
        const int r0 = bx * 32, b0 = by * 32;
#pragma unroll
        for (int j = 0; j < 32; j += 8)
            tile[ty + j][tx] = in[(size_t)(b0 + ty + j) * RES_DIM + r0 + tx];
        __syncthreads();
#pragma unroll
        for (int i = threadIdx.x; i < 512; i += 256) {   // 32 r x 16 pairs
            int rl = i >> 4, pl = i & 15;
            uint32_t lo = f32_to_bf16_rne(tile[2 * pl + 0][rl]);
            uint32_t hi = f32_to_bf16_rne(tile[2 * pl + 1][rl]);
            st2[(size_t)(r0 + rl) * 64 + (b0 >> 1) + pl] = lo | (hi << 16);
        }
    } else {
        const int t  = (blockIdx.x - CONV_BLOCKS) * 256 + threadIdx.x;
        const int k4 = t * 4;
        if (k4 >= NNZ) return;
        if (k4 + 4 <= NNZ) {                 // full int4 (NNZ % 4 == 1)
            const int4 R = *(const int4*)(rows + k4);
            if (k4 == 0)
                for (int r = 0; r <= R.x; ++r) row_start[r] = 0;
            const int rn = rows[k4 + 4];
            for (int r = R.x + 1; r <= R.y; ++r) row_start[r] = k4 + 1;
            for (int r = R.y + 1; r <= R.z; ++r) row_start[r] = k4 + 2;
            for (int r = R.z + 1; r <= R.w; ++r) row_start[r] = k4 + 3;
            for (int r = R.w + 1; r <= rn;  ++r) row_start[r] = k4 + 4;
        } else {                             // k4 == NNZ-1 exactly
            const int r1 = rows[k4];
            for (int r = r1 + 1; r <= RES_DIM; ++r) row_start[r] = NNZ;
        }
    }
}

// ---------------------------------------------------------------------------
// Kernel 2: spmm + fused epilogue (round-8 structure). One wave per row,
// 4 rows/block. 16-lane group g owns 4 contiguous nnz (one int4/float4
// broadcast pack); lane j = l&15 holds batches 8j..8j+7 (uint4 = 8 bf16
// per gather). Phase-split 2-slot pipeline; drain stashes Vt.
// launch_bounds(256,8): compiler already emits 64 VGPR under a 128 cap;
// the 64-VGPR cap doubles resident waves (8 blocks/CU) for 2x outstanding
// L1 misses — the gather is latency/MSHR-bound, not BW-bound.
// ---------------------------------------------------------------------------
#define FMA8(G, v)                                              \
    do {                                                        \
        a0 = fmaf(v, __uint_as_float((G).x << 16), a0);         \
        a1 = fmaf(v, __uint_as_float((G).x & 0xffff0000u), a1); \
        a2 = fmaf(v, __uint_as_float((G).y << 16), a2);         \
        a3 = fmaf(v, __uint_as_float((G).y & 0xffff0000u), a3); \
        a4 = fmaf(v, __uint_as_float((G).z << 16), a4);         \
        a5 = fmaf(v, __uint_as_float((G).z & 0xffff0000u), a5); \
        a6 = fmaf(v, __uint_as_float((G).w << 16), a6);         \
        a7 = fmaf(v, __uint_as_float((G).w & 0xffff0000u), a7); \
    } while (0)

#define LOADCV(s, u)                                            \
    do {                                                        \
        const int base_ = ka + ((u) << 4) + 4 * g;              \
        C##s = *(const int4*)(cols + base_);                    \
        V##s = *(const float4*)(vals + base_);                  \
    } while (0)

#define LOADG(s)                                                              \
    do {                                                                      \
        G##s##0 = *(const uint4*)(stb + (((uint32_t)C##s.x << 8) + joff));    \
        G##s##1 = *(const uint4*)(stb + (((uint32_t)C##s.y << 8) + joff));    \
        G##s##2 = *(const uint4*)(stb + (((uint32_t)C##s.z << 8) + joff));    \
        G##s##3 = *(const uint4*)(stb + (((uint32_t)C##s.w << 8) + joff));    \
    } while (0)

#define CONS_T(s)                                               \
    do {                                                        \
        FMA8(G##s##0, Vt.x);                                    \
        FMA8(G##s##1, Vt.y);                                    \
        FMA8(G##s##2, Vt.z);                                    \
        FMA8(G##s##3, Vt.w);                                    \
    } while (0)

#define CONS(s)                                                 \
    do {                                                        \
        FMA8(G##s##0, V##s.x);                                  \
        FMA8(G##s##1, V##s.y);                                  \
        FMA8(G##s##2, V##s.z);                                  \
        FMA8(G##s##3, V##s.w);                                  \
    } while (0)

__global__ __launch_bounds__(256, 8) void spmm_kernel(
    const float* __restrict__ vals, const int* __restrict__ cols,
    const int* __restrict__ row_start, const uint32_t* __restrict__ st2,
    const float* __restrict__ proj, const float* __restrict__ res,
    float* __restrict__ out) {
    const int t = threadIdx.x;
    const int w = t >> 6;          // wave -> row within block
    const int l = t & 63;
    const int g = l >> 4;          // 4-nnz pack slot
    const int j = l & 15;          // batch slot: batches 8j..8j+7
    // XCD-bijective swizzle over 2048 blocks (2048 = 8 * 256)
    const int bp = (blockIdx.x & 7) * 256 + (blockIdx.x >> 3);
    const int r0 = bp * 4;
    const int r  = r0 + w;

    const int ks = row_start[r];
    const int ke = row_start[r + 1];
    const int ka = min(ke, (ks + 3) & ~3);   // 16B-align start
    const int U  = (ke - ka) >> 4;           // full 16-nnz units
    const int ts = ka + (U << 4);            // tail start (<16 left)

    const char* stb = (const char*)st2;
    const uint32_t joff = (uint32_t)j << 4;
    float a0 = 0, a1 = 0, a2 = 0, a3 = 0, a4 = 0, a5 = 0, a6 = 0, a7 = 0;

    // head (<=3 nnz, unaligned)
    if (ks < ka) {
        const int kk = ks + g;
        int c = 0; float v = 0.0f;
        if (kk < ka) { c = cols[kk]; v = vals[kk]; }
        const uint4 G = *(const uint4*)(stb + (((uint32_t)c << 8) + joff));
        FMA8(G, v);
    }
    // tail (<=15 nnz)
    if (ts < ke) {
#pragma unroll
        for (int i2 = 0; i2 < 4; ++i2) {
            const int kk = ts + 4 * i2 + g;
            int c = 0; float v = 0.0f;
            if (kk < ke) { c = cols[kk]; v = vals[kk]; }
            const uint4 G = *(const uint4*)(stb + (((uint32_t)c << 8) + joff));
            FMA8(G, v);
        }
    }

    // ---- phase-split pipelined main loop ----
    int4 CA, CB; float4 VA, VB;
    uint4 GA0, GA1, GA2, GA3, GB0, GB1, GB2, GB3;

    if (U >= 4) {
        LOADCV(A, 0);
        LOADCV(B, 1);
        LOADG(A);                              // unit 0
        int i = 0;
        for (; i + 4 <= U; i += 2) {
            {   // unit i (slot A); prefetch CV(i+2), G(i+1)
                const float4 Vt = VA;
                LOADCV(A, i + 2);
                LOADG(B);                      // unit i+1, CB loaded 1 iter ago
                CONS_T(A);
            }
            {   // unit i+1 (slot B); prefetch CV(i+3), G(i+2)
                const float4 Vt = VB;
                LOADCV(B, i + 3);
                LOADG(A);                      // unit i+2, CA loaded above
                CONS_T(B);
            }
        }
        // exit: GA/VA = unit i (ready); CB/VB = unit i+1 (cols ready)
        LOADG(B);                              // unit i+1 gathers
        if (i + 2 < U) {                       // 3 units left: i, i+1, i+2
            const float4 Vt = VA;              // stash BEFORE clobbering slot A
            LOADCV(A, i + 2);
            CONS_T(A);                         // unit i
            LOADG(A);                          // unit i+2
            CONS(B);                           // unit i+1
            CONS(A);                           // unit i+2
        } else {                               // 2 units left: i, i+1
            CONS(A);
            CONS(B);
        }
    } else {
        for (int u = 0; u < U; ++u) { LOADCV(A, u); LOADG(A); CONS(A); }
    }

    // combine the 4 nnz-groups within the wave
    a0 += __shfl_xor(a0, 16, 64); a0 += __shfl_xor(a0, 32, 64);
    a1 += __shfl_xor(a1, 16, 64); a1 += __shfl_xor(a1, 32, 64);
    a2 += __shfl_xor(a2, 16, 64); a2 += __shfl_xor(a2, 32, 64);
    a3 += __shfl_xor(a3, 16, 64); a3 += __shfl_xor(a3, 32, 64);
    a4 += __shfl_xor(a4, 16, 64); a4 += __shfl_xor(a4, 32, 64);
    a5 += __shfl_xor(a5, 16, 64); a5 += __shfl_xor(a5, 32, 64);
    a6 += __shfl_xor(a6, 16, 64); a6 += __shfl_xor(a6, 32, 64);
    a7 += __shfl_xor(a7, 16, 64); a7 += __shfl_xor(a7, 32, 64);

    // stage y[4 rows][128 b] in LDS, then fused tanh/leak epilogue
    __shared__ float ly[4][BATCH];
    if (l < 16) {
        *(float4*)&ly[w][8 * j + 0] = make_float4(a0, a1, a2, a3);
        *(float4*)&ly[w][8 * j + 4] = make_float4(a4, a5, a6, a7);
    }
    __syncthreads();
    if (t < BATCH) {
        const int b = t;
        const size_t oi = (size_t)b * RES_DIM + r0;
        const float4 pj = *(const float4*)(proj + oi);
        const float4 rs = *(const float4*)(res + oi);
        float4 o;
        o.x = LEAK * fast_tanh(ly[0][b] + pj.x + BIAS) + (1.0f - LEAK) * rs.x;
        o.y = LEAK * fast_tanh(ly[1][b] + pj.y + BIAS) + (1.0f - LEAK) * rs.y;
        o.z = LEAK * fast_tanh(ly[2][b] + pj.z + BIAS) + (1.0f - LEAK) * rs.z;
        o.w = LEAK * fast_tanh(ly[3][b] + pj.w + BIAS) + (1.0f - LEAK) * rs.w;
        *(float4*)(out + oi) = o;
    }
}

// ---------------------------------------------------------------------------
extern "C" void kernel_launch(void* const* d_in, const int* in_sizes, int n_in,
                              void* d_out, int out_size, void* d_ws, size_t ws_size,
                              hipStream_t stream) {
    const float* proj      = (const float*)d_in[0];
    const float* res_state = (const float*)d_in[1];
    const float* wr_vals   = (const float*)d_in[2];
    const int*   wr_rows   = (const int*)d_in[3];
    const int*   wr_cols   = (const int*)d_in[4];
    float*       out       = (float*)d_out;

    // ws layout: st2 (2 MB) | row_start (32.8 KB)
    uint8_t*  ws        = (uint8_t*)d_ws;
    uint32_t* st2       = (uint32_t*)ws;
    int*      row_start = (int*)(ws + 2097152);

    prep_kernel<<<CONV_BLOCKS + BND_BLOCKS, 256, 0, stream>>>(
        res_state, st2, wr_rows, row_start);

    spmm_kernel<<<RES_DIM / 4, 256, 0, stream>>>(
        wr_vals, wr_cols, row_start, st2, proj, res_state, out);
}

// Round 14
// 47.799 us; speedup vs baseline: 3.3587x; 3.3587x over previous
//
#include <hip/hip_runtime.h>
#include <stdint.h>

#define RES_DIM 8192
#define BATCH   128
#define NNZ     1342177
#define LEAK    0.6f
#define BIAS    1.6f

#define CONV_BLOCKS 1024                          // (RES_DIM/32) * (BATCH/32)
#define BND_THREADS ((NNZ + 3) / 4)               // 335545
#define BND_BLOCKS  ((BND_THREADS + 255) / 256)   // 1311

typedef unsigned int u32x4 __attribute__((ext_vector_type(4)));

// ---------------------------------------------------------------------------
// helpers
// ---------------------------------------------------------------------------
__device__ __forceinline__ float fast_tanh(float x) {
    float e = __expf(2.0f * x);
    return 1.0f - 2.0f / (e + 1.0f);
}

__device__ __forceinline__ uint32_t f32_to_bf16_rne(float f) {
    uint32_t u = __float_as_uint(f);
    return (u + 0x7fffu + ((u >> 16) & 1u)) >> 16;
}

// ---------------------------------------------------------------------------
// Kernel 1 (fused prep): conv (bf16-pack transpose) + rowptr boundary detect
// ---------------------------------------------------------------------------
__global__ __launch_bounds__(256) void prep_kernel(
    const float* __restrict__ in, uint32_t* __restrict__ st2,
    const int* __restrict__ rows, int* __restrict__ row_start) {
    if (blockIdx.x < CONV_BLOCKS) {
        __shared__ float tile[32][33];
        const int bx = blockIdx.x & 255;     // r-tile
        const int by = blockIdx.x >> 8;      // b-tile
        const int tx = threadIdx.x & 31, ty = threadIdx.x >> 5;  // 32x8
        const int r0 = bx * 32, b0 = by * 32;
#pragma unroll
        for (int j = 0; j < 32; j += 8)
            tile[ty + j][tx] = in[(size_t)(b0 + ty + j) * RES_DIM + r0 + tx];
        __syncthreads();
#pragma unroll
        for (int i = threadIdx.x; i < 512; i += 256) {   // 32 r x 16 pairs
            int rl = i >> 4, pl = i & 15;
            uint32_t lo = f32_to_bf16_rne(tile[2 * pl + 0][rl]);
            uint32_t hi = f32_to_bf16_rne(tile[2 * pl + 1][rl]);
            st2[(size_t)(r0 + rl) * 64 + (b0 >> 1) + pl] = lo | (hi << 16);
        }
    } else {
        const int t  = (blockIdx.x - CONV_BLOCKS) * 256 + threadIdx.x;
        const int k4 = t * 4;
        if (k4 >= NNZ) return;
        if (k4 + 4 <= NNZ) {                 // full int4 (NNZ % 4 == 1)
            const int4 R = *(const int4*)(rows + k4);
            if (k4 == 0)
                for (int r = 0; r <= R.x; ++r) row_start[r] = 0;
            const int rn = rows[k4 + 4];
            for (int r = R.x + 1; r <= R.y; ++r) row_start[r] = k4 + 1;
            for (int r = R.y + 1; r <= R.z; ++r) row_start[r] = k4 + 2;
            for (int r = R.z + 1; r <= R.w; ++r) row_start[r] = k4 + 3;
            for (int r = R.w + 1; r <= rn;  ++r) row_start[r] = k4 + 4;
        } else {                             // k4 == NNZ-1 exactly
            const int r1 = rows[k4];
            for (int r = r1 + 1; r <= RES_DIM; ++r) row_start[r] = NNZ;
        }
    }
}

// ---------------------------------------------------------------------------
// Kernel 2: spmm + fused epilogue (round-8 structure, (256,4) restored).
// One wave per row, 4 rows/block; 16-lane group g owns 4 contiguous nnz;
// lane j holds batches 8j..8j+7. Phase-split 2-slot pipeline.
// CHANGE vs round 8: pipeline gathers use __builtin_nontemporal_load (nt) —
// the 2 MB table can't live in the 32 KB L1 (hit rate ~1.5%), so skipping
// L1 allocation removes tag/allocation/MSHR overhead per miss. L2 caching
// must be preserved for the table; if FETCH_SIZE explodes, nt broke L2
// residency and this change gets reverted.
// ---------------------------------------------------------------------------
#define FMA8(G, v)                                              \
    do {                                                        \
        a0 = fmaf(v, __uint_as_float((G).x << 16), a0);         \
        a1 = fmaf(v, __uint_as_float((G).x & 0xffff0000u), a1); \
        a2 = fmaf(v, __uint_as_float((G).y << 16), a2);         \
        a3 = fmaf(v, __uint_as_float((G).y & 0xffff0000u), a3); \
        a4 = fmaf(v, __uint_as_float((G).z << 16), a4);         \
        a5 = fmaf(v, __uint_as_float((G).z & 0xffff0000u), a5); \
        a6 = fmaf(v, __uint_as_float((G).w << 16), a6);         \
        a7 = fmaf(v, __uint_as_float((G).w & 0xffff0000u), a7); \
    } while (0)

#define LOADCV(s, u)                                            \
    do {                                                        \
        const int base_ = ka + ((u) << 4) + 4 * g;              \
        C##s = *(const int4*)(cols + base_);                    \
        V##s = *(const float4*)(vals + base_);                  \
    } while (0)

#define LOADG(s)                                                                            \
    do {                                                                                    \
        G##s##0 = __builtin_nontemporal_load((const u32x4*)(stb + (((uint32_t)C##s.x << 8) + joff))); \
        G##s##1 = __builtin_nontemporal_load((const u32x4*)(stb + (((uint32_t)C##s.y << 8) + joff))); \
        G##s##2 = __builtin_nontemporal_load((const u32x4*)(stb + (((uint32_t)C##s.z << 8) + joff))); \
        G##s##3 = __builtin_nontemporal_load((const u32x4*)(stb + (((uint32_t)C##s.w << 8) + joff))); \
    } while (0)

#define CONS_T(s)                                               \
    do {                                                        \
        FMA8(G##s##0, Vt.x);                                    \
        FMA8(G##s##1, Vt.y);                                    \
        FMA8(G##s##2, Vt.z);                                    \
        FMA8(G##s##3, Vt.w);                                    \
    } while (0)

#define CONS(s)                                                 \
    do {                                                        \
        FMA8(G##s##0, V##s.x);                                  \
        FMA8(G##s##1, V##s.y);                                  \
        FMA8(G##s##2, V##s.z);                                  \
        FMA8(G##s##3, V##s.w);                                  \
    } while (0)

__global__ __launch_bounds__(256, 4) void spmm_kernel(
    const float* __restrict__ vals, const int* __restrict__ cols,
    const int* __restrict__ row_start, const uint32_t* __restrict__ st2,
    const float* __restrict__ proj, const float* __restrict__ res,
    float* __restrict__ out) {
    const int t = threadIdx.x;
    const int w = t >> 6;          // wave -> row within block
    const int l = t & 63;
    const int g = l >> 4;          // 4-nnz pack slot
    const int j = l & 15;          // batch slot: batches 8j..8j+7
    // XCD-bijective swizzle over 2048 blocks (2048 = 8 * 256)
    const int bp = (blockIdx.x & 7) * 256 + (blockIdx.x >> 3);
    const int r0 = bp * 4;
    const int r  = r0 + w;

    const int ks = row_start[r];
    const int ke = row_start[r + 1];
    const int ka = min(ke, (ks + 3) & ~3);   // 16B-align start
    const int U  = (ke - ka) >> 4;           // full 16-nnz units
    const int ts = ka + (U << 4);            // tail start (<16 left)

    const char* stb = (const char*)st2;
    const uint32_t joff = (uint32_t)j << 4;
    float a0 = 0, a1 = 0, a2 = 0, a3 = 0, a4 = 0, a5 = 0, a6 = 0, a7 = 0;

    // head (<=3 nnz, unaligned)
    if (ks < ka) {
        const int kk = ks + g;
        int c = 0; float v = 0.0f;
        if (kk < ka) { c = cols[kk]; v = vals[kk]; }
        const uint4 G = *(const uint4*)(stb + (((uint32_t)c << 8) + joff));
        FMA8(G, v);
    }
    // tail (<=15 nnz)
    if (ts < ke) {
#pragma unroll
        for (int i2 = 0; i2 < 4; ++i2) {
            const int kk = ts + 4 * i2 + g;
            int c = 0; float v = 0.0f;
            if (kk < ke) { c = cols[kk]; v = vals[kk]; }
            const uint4 G = *(const uint4*)(stb + (((uint32_t)c << 8) + joff));
            FMA8(G, v);
        }
    }

    // ---- phase-split pipelined main loop ----
    int4 CA, CB; float4 VA, VB;
    u32x4 GA0, GA1, GA2, GA3, GB0, GB1, GB2, GB3;

    if (U >= 4) {
        LOADCV(A, 0);
        LOADCV(B, 1);
        LOADG(A);                              // unit 0
        int i = 0;
        for (; i + 4 <= U; i += 2) {
            {   // unit i (slot A); prefetch CV(i+2), G(i+1)
                const float4 Vt = VA;
                LOADCV(A, i + 2);
                LOADG(B);                      // unit i+1, CB loaded 1 iter ago
                CONS_T(A);
            }
            {   // unit i+1 (slot B); prefetch CV(i+3), G(i+2)
                const float4 Vt = VB;
                LOADCV(B, i + 3);
                LOADG(A);                      // unit i+2, CA loaded above
                CONS_T(B);
            }
        }
        // exit: GA/VA = unit i (ready); CB/VB = unit i+1 (cols ready)
        LOADG(B);                              // unit i+1 gathers
        if (i + 2 < U) {                       // 3 units left: i, i+1, i+2
            const float4 Vt = VA;              // stash BEFORE clobbering slot A
            LOADCV(A, i + 2);
            CONS_T(A);                         // unit i
            LOADG(A);                          // unit i+2
            CONS(B);                           // unit i+1
            CONS(A);                           // unit i+2
        } else {                               // 2 units left: i, i+1
            CONS(A);
            CONS(B);
        }
    } else {
        for (int u = 0; u < U; ++u) { LOADCV(A, u); LOADG(A); CONS(A); }
    }

    // combine the 4 nnz-groups within the wave
    a0 += __shfl_xor(a0, 16, 64); a0 += __shfl_xor(a0, 32, 64);
    a1 += __shfl_xor(a1, 16, 64); a1 += __shfl_xor(a1, 32, 64);
    a2 += __shfl_xor(a2, 16, 64); a2 += __shfl_xor(a2, 32, 64);
    a3 += __shfl_xor(a3, 16, 64); a3 += __shfl_xor(a3, 32, 64);
    a4 += __shfl_xor(a4, 16, 64); a4 += __shfl_xor(a4, 32, 64);
    a5 += __shfl_xor(a5, 16, 64); a5 += __shfl_xor(a5, 32, 64);
    a6 += __shfl_xor(a6, 16, 64); a6 += __shfl_xor(a6, 32, 64);
    a7 += __shfl_xor(a7, 16, 64); a7 += __shfl_xor(a7, 32, 64);

    // stage y[4 rows][128 b] in LDS, then fused tanh/leak epilogue
    __shared__ float ly[4][BATCH];
    if (l < 16) {
        *(float4*)&ly[w][8 * j + 0] = make_float4(a0, a1, a2, a3);
        *(float4*)&ly[w][8 * j + 4] = make_float4(a4, a5, a6, a7);
    }
    __syncthreads();
    if (t < BATCH) {
        const int b = t;
        const size_t oi = (size_t)b * RES_DIM + r0;
        const float4 pj = *(const float4*)(proj + oi);
        const float4 rs = *(const float4*)(res + oi);
        float4 o;
        o.x = LEAK * fast_tanh(ly[0][b] + pj.x + BIAS) + (1.0f - LEAK) * rs.x;
        o.y = LEAK * fast_tanh(ly[1][b] + pj.y + BIAS) + (1.0f - LEAK) * rs.y;
        o.z = LEAK * fast_tanh(ly[2][b] + pj.z + BIAS) + (1.0f - LEAK) * rs.z;
        o.w = LEAK * fast_tanh(ly[3][b] + pj.w + BIAS) + (1.0f - LEAK) * rs.w;
        *(float4*)(out + oi) = o;
    }
}

// ---------------------------------------------------------------------------
extern "C" void kernel_launch(void* const* d_in, const int* in_sizes, int n_in,
                              void* d_out, int out_size, void* d_ws, size_t ws_size,
                              hipStream_t stream) {
    const float* proj      = (const float*)d_in[0];
    const float* res_state = (const float*)d_in[1];
    const float* wr_vals   = (const float*)d_in[2];
    const int*   wr_rows   = (const int*)d_in[3];
    const int*   wr_cols   = (const int*)d_in[4];
    float*       out       = (float*)d_out;

    // ws layout: st2 (2 MB) | row_start (32.8 KB)
    uint8_t*  ws        = (uint8_t*)d_ws;
    uint32_t* st2       = (uint32_t*)ws;
    int*      row_start = (int*)(ws + 2097152);

    prep_kernel<<<CONV_BLOCKS + BND_BLOCKS, 256, 0, stream>>>(
        res_state, st2, wr_rows, row_start);

    spmm_kernel<<<RES_DIM / 4, 256, 0, stream>>>(
        wr_vals, wr_cols, row_start, st2, proj, res_state, out);
}

// Round 16
// 34.066 us; speedup vs baseline: 4.7127x; 1.4031x over previous
//
#include <hip/hip_runtime.h>
#include <stdint.h>

#define RES_DIM 8192
#define BATCH   128
#define NNZ     1342177
#define LEAK    0.6f
#define BIAS    1.6f

#define CONV_BLOCKS 1024                          // (RES_DIM/32) * (BATCH/32)
#define BND_THREADS ((NNZ + 3) / 4)               // 335545
#define BND_BLOCKS  ((BND_THREADS + 255) / 256)   // 1311

// ---------------------------------------------------------------------------
// helpers
// ---------------------------------------------------------------------------
__device__ __forceinline__ float fast_tanh(float x) {
    float e = __expf(2.0f * x);
    return 1.0f - 2.0f / (e + 1.0f);
}

__device__ __forceinline__ uint32_t f32_to_bf16_rne(float f) {
    uint32_t u = __float_as_uint(f);
    return (u + 0x7fffu + ((u >> 16) & 1u)) >> 16;
}

// ---------------------------------------------------------------------------
// Kernel 1 (fused prep): conv (bf16-pack transpose) + rowptr boundary detect
// ---------------------------------------------------------------------------
__global__ __launch_bounds__(256) void prep_kernel(
    const float* __restrict__ in, uint32_t* __restrict__ st2,
    const int* __restrict__ rows, int* __restrict__ row_start) {
    if (blockIdx.x < CONV_BLOCKS) {
        __shared__ float tile[32][33];
        const int bx = blockIdx.x & 255;     // r-tile
        const int by = blockIdx.x >> 8;      // b-tile
        const int tx = threadIdx.x & 31, ty = threadIdx.x >> 5;  // 32x8
        const int r0 = bx * 32, b0 = by * 32;
#pragma unroll
        for (int j = 0; j < 32; j += 8)
            tile[ty + j][tx] = in[(size_t)(b0 + ty + j) * RES_DIM + r0 + tx];
        __syncthreads();
#pragma unroll
        for (int i = threadIdx.x; i < 512; i += 256) {   // 32 r x 16 pairs
            int rl = i >> 4, pl = i & 15;
            uint32_t lo = f32_to_bf16_rne(tile[2 * pl + 0][rl]);
            uint32_t hi = f32_to_bf16_rne(tile[2 * pl + 1][rl]);
            st2[(size_t)(r0 + rl) * 64 + (b0 >> 1) + pl] = lo | (hi << 16);
        }
    } else {
        const int t  = (blockIdx.x - CONV_BLOCKS) * 256 + threadIdx.x;
        const int k4 = t * 4;
        if (k4 >= NNZ) return;
        if (k4 + 4 <= NNZ) {                 // full int4 (NNZ % 4 == 1)
            const int4 R = *(const int4*)(rows + k4);
            if (k4 == 0)
                for (int r = 0; r <= R.x; ++r) row_start[r] = 0;
            const int rn = rows[k4 + 4];
            for (int r = R.x + 1; r <= R.y; ++r) row_start[r] = k4 + 1;
            for (int r = R.y + 1; r <= R.z; ++r) row_start[r] = k4 + 2;
            for (int r = R.z + 1; r <= R.w; ++r) row_start[r] = k4 + 3;
            for (int r = R.w + 1; r <= rn;  ++r) row_start[r] = k4 + 4;
        } else {                             // k4 == NNZ-1 exactly
            const int r1 = rows[k4];
            for (int r = r1 + 1; r <= RES_DIM; ++r) row_start[r] = NNZ;
        }
    }
}

// ---------------------------------------------------------------------------
// Kernel 2: spmm + fused epilogue (round-8 proven structure, best measured:
// 34.27 us total). One wave per row, 4 rows/block. 16-lane group g owns 4
// contiguous nnz (one int4/float4 broadcast pack); lane j = l&15 holds
// batches 8j..8j+7 (uint4 = 8 bf16 per gather; 4 nnz per gather instr).
// Phase-split 2-slot pipeline; drain stashes Vt before slot reuse.
// S ~= 22.7 us is the random-256B-gather path limit (MSHR/TA line rate):
// invariant across 5 gather structures, pipeline depth, occupancy, and
// cache-policy hints (rounds 2-14).
// ---------------------------------------------------------------------------
#define FMA8(G, v)                                              \
    do {                                                        \
        a0 = fmaf(v, __uint_as_float((G).x << 16), a0);         \
        a1 = fmaf(v, __uint_as_float((G).x & 0xffff0000u), a1); \
        a2 = fmaf(v, __uint_as_float((G).y << 16), a2);         \
        a3 = fmaf(v, __uint_as_float((G).y & 0xffff0000u), a3); \
        a4 = fmaf(v, __uint_as_float((G).z << 16), a4);         \
        a5 = fmaf(v, __uint_as_float((G).z & 0xffff0000u), a5); \
        a6 = fmaf(v, __uint_as_float((G).w << 16), a6);         \
        a7 = fmaf(v, __uint_as_float((G).w & 0xffff0000u), a7); \
    } while (0)

#define LOADCV(s, u)                                            \
    do {                                                        \
        const int base_ = ka + ((u) << 4) + 4 * g;              \
        C##s = *(const int4*)(cols + base_);                    \
        V##s = *(const float4*)(vals + base_);                  \
    } while (0)

#define LOADG(s)                                                              \
    do {                                                                      \
        G##s##0 = *(const uint4*)(stb + (((uint32_t)C##s.x << 8) + joff));    \
        G##s##1 = *(const uint4*)(stb + (((uint32_t)C##s.y << 8) + joff));    \
        G##s##2 = *(const uint4*)(stb + (((uint32_t)C##s.z << 8) + joff));    \
        G##s##3 = *(const uint4*)(stb + (((uint32_t)C##s.w << 8) + joff));    \
    } while (0)

#define CONS_T(s)                                               \
    do {                                                        \
        FMA8(G##s##0, Vt.x);                                    \
        FMA8(G##s##1, Vt.y);                                    \
        FMA8(G##s##2, Vt.z);                                    \
        FMA8(G##s##3, Vt.w);                                    \
    } while (0)

#define CONS(s)                                                 \
    do {                                                        \
        FMA8(G##s##0, V##s.x);                                  \
        FMA8(G##s##1, V##s.y);                                  \
        FMA8(G##s##2, V##s.z);                                  \
        FMA8(G##s##3, V##s.w);                                  \
    } while (0)

__global__ __launch_bounds__(256, 4) void spmm_kernel(
    const float* __restrict__ vals, const int* __restrict__ cols,
    const int* __restrict__ row_start, const uint32_t* __restrict__ st2,
    const float* __restrict__ proj, const float* __restrict__ res,
    float* __restrict__ out) {
    const int t = threadIdx.x;
    const int w = t >> 6;          // wave -> row within block
    const int l = t & 63;
    const int g = l >> 4;          // 4-nnz pack slot
    const int j = l & 15;          // batch slot: batches 8j..8j+7
    // XCD-bijective swizzle over 2048 blocks (2048 = 8 * 256)
    const int bp = (blockIdx.x & 7) * 256 + (blockIdx.x >> 3);
    const int r0 = bp * 4;
    const int r  = r0 + w;

    const int ks = row_start[r];
    const int ke = row_start[r + 1];
    const int ka = min(ke, (ks + 3) & ~3);   // 16B-align start
    const int U  = (ke - ka) >> 4;           // full 16-nnz units
    const int ts = ka + (U << 4);            // tail start (<16 left)

    const char* stb = (const char*)st2;
    const uint32_t joff = (uint32_t)j << 4;
    float a0 = 0, a1 = 0, a2 = 0, a3 = 0, a4 = 0, a5 = 0, a6 = 0, a7 = 0;

    // head (<=3 nnz, unaligned)
    if (ks < ka) {
        const int kk = ks + g;
        int c = 0; float v = 0.0f;
        if (kk < ka) { c = cols[kk]; v = vals[kk]; }
        const uint4 G = *(const uint4*)(stb + (((uint32_t)c << 8) + joff));
        FMA8(G, v);
    }
    // tail (<=15 nnz)
    if (ts < ke) {
#pragma unroll
        for (int i2 = 0; i2 < 4; ++i2) {
            const int kk = ts + 4 * i2 + g;
            int c = 0; float v = 0.0f;
            if (kk < ke) { c = cols[kk]; v = vals[kk]; }
            const uint4 G = *(const uint4*)(stb + (((uint32_t)c << 8) + joff));
            FMA8(G, v);
        }
    }

    // ---- phase-split pipelined main loop ----
    int4 CA, CB; float4 VA, VB;
    uint4 GA0, GA1, GA2, GA3, GB0, GB1, GB2, GB3;

    if (U >= 4) {
        LOADCV(A, 0);
        LOADCV(B, 1);
        LOADG(A);                              // unit 0
        int i = 0;
        for (; i + 4 <= U; i += 2) {
            {   // unit i (slot A); prefetch CV(i+2), G(i+1)
                const float4 Vt = VA;
                LOADCV(A, i + 2);
                LOADG(B);                      // unit i+1, CB loaded 1 iter ago
                CONS_T(A);
            }
            {   // unit i+1 (slot B); prefetch CV(i+3), G(i+2)
                const float4 Vt = VB;
                LOADCV(B, i + 3);
                LOADG(A);                      // unit i+2, CA loaded above
                CONS_T(B);
            }
        }
        // exit: GA/VA = unit i (ready); CB/VB = unit i+1 (cols ready)
        LOADG(B);                              // unit i+1 gathers
        if (i + 2 < U) {                       // 3 units left: i, i+1, i+2
            const float4 Vt = VA;              // stash BEFORE clobbering slot A
            LOADCV(A, i + 2);
            CONS_T(A);                         // unit i
            LOADG(A);                          // unit i+2
            CONS(B);                           // unit i+1
            CONS(A);                           // unit i+2
        } else {                               // 2 units left: i, i+1
            CONS(A);
            CONS(B);
        }
    } else {
        for (int u = 0; u < U; ++u) { LOADCV(A, u); LOADG(A); CONS(A); }
    }

    // combine the 4 nnz-groups within the wave
    a0 += __shfl_xor(a0, 16, 64); a0 += __shfl_xor(a0, 32, 64);
    a1 += __shfl_xor(a1, 16, 64); a1 += __shfl_xor(a1, 32, 64);
    a2 += __shfl_xor(a2, 16, 64); a2 += __shfl_xor(a2, 32, 64);
    a3 += __shfl_xor(a3, 16, 64); a3 += __shfl_xor(a3, 32, 64);
    a4 += __shfl_xor(a4, 16, 64); a4 += __shfl_xor(a4, 32, 64);
    a5 += __shfl_xor(a5, 16, 64); a5 += __shfl_xor(a5, 32, 64);
    a6 += __shfl_xor(a6, 16, 64); a6 += __shfl_xor(a6, 32, 64);
    a7 += __shfl_xor(a7, 16, 64); a7 += __shfl_xor(a7, 32, 64);

    // stage y[4 rows][128 b] in LDS, then fused tanh/leak epilogue
    __shared__ float ly[4][BATCH];
    if (l < 16) {
        *(float4*)&ly[w][8 * j + 0] = make_float4(a0, a1, a2, a3);
        *(float4*)&ly[w][8 * j + 4] = make_float4(a4, a5, a6, a7);
    }
    __syncthreads();
    if (t < BATCH) {
        const int b = t;
        const size_t oi = (size_t)b * RES_DIM + r0;
        const float4 pj = *(const float4*)(proj + oi);
        const float4 rs = *(const float4*)(res + oi);
        float4 o;
        o.x = LEAK * fast_tanh(ly[0][b] + pj.x + BIAS) + (1.0f - LEAK) * rs.x;
        o.y = LEAK * fast_tanh(ly[1][b] + pj.y + BIAS) + (1.0f - LEAK) * rs.y;
        o.z = LEAK * fast_tanh(ly[2][b] + pj.z + BIAS) + (1.0f - LEAK) * rs.z;
        o.w = LEAK * fast_tanh(ly[3][b] + pj.w + BIAS) + (1.0f - LEAK) * rs.w;
        *(float4*)(out + oi) = o;
    }
}

// ---------------------------------------------------------------------------
extern "C" void kernel_launch(void* const* d_in, const int* in_sizes, int n_in,
                              void* d_out, int out_size, void* d_ws, size_t ws_size,
                              hipStream_t stream) {
    const float* proj      = (const float*)d_in[0];
    const float* res_state = (const float*)d_in[1];
    const float* wr_vals   = (const float*)d_in[2];
    const int*   wr_rows   = (const int*)d_in[3];
    const int*   wr_cols   = (const int*)d_in[4];
    float*       out       = (float*)d_out;

    // ws layout: st2 (2 MB) | row_start (32.8 KB)
    uint8_t*  ws        = (uint8_t*)d_ws;
    uint32_t* st2       = (uint32_t*)ws;
    int*      row_start = (int*)(ws + 2097152);

    prep_kernel<<<CONV_BLOCKS + BND_BLOCKS, 256, 0, stream>>>(
        res_state, st2, wr_rows, row_start);

    spmm_kernel<<<RES_DIM / 4, 256, 0, stream>>>(
        wr_vals, wr_cols, row_start, st2, proj, res_state, out);
}